// Round 17
// baseline (222.390 us; speedup 1.0000x reference)
//
#include <hip/hip_runtime.h>
#include <hip/hip_cooperative_groups.h>
#include <math.h>

namespace cg = cooperative_groups;

// Problem constants
#define NB 16
#define NL 128
#define DIN 512
#define NH 256
#define NTAGS 45
#define NM (NB*NL)          // 2048 rows
#define NJ (NL+1)           // 129 arc columns

// ws layout (floats)
#define H_OFF     0                        // 2 slabs of NM*NH (K-split partials)
#define U_OFF     (2*NM*NH)                // 1 slab  (u = hidden@Wa + bp)
#define HV_OFF    (3*NM*NH)                // 1 slab  (hv = hidden@Wb)
#define VROOT_OFF (4*NM*NH)                // NH
#define ACC_OFF   (VROOT_OFF + NH)         // [0]=loss sum

// Shared-memory arena: max(phaseA 27.6KB, phaseB 26.6KB, phaseC 144.7KB)
#define SMEM_BYTES 145408

// ---------------------------------------------------------------------------
// Fused cooperative kernel: 256 blocks x 512 threads, 1 block/CU (LDS-bound).
// Phase A = k1 (2 tiles/block, two 256-thread sub-blocks in lockstep: joint
// __syncthreads is safe — identical chunk counts) + vroot epilogue with
// unconditional barriers. Phase B = k2 (2 tiles/block). Phase C = round-14
// k3 verbatim (512 thr, full v-tile in LDS, b128 dual-j reads). grid.sync()
// between phases; block 0 finalizes after a last sync (no done counter).
// Eliminates 2 inter-kernel gaps + 2 launch/drain overheads.
// ---------------------------------------------------------------------------
__global__ __launch_bounds__(512) void fused_kernel(
    const float* __restrict__ A,    // 2048 x 512 (contextualized)
    const float* __restrict__ W1,   // 512 x 256
    const float* __restrict__ Wp,   // 512 x 256
    const float* __restrict__ root, // 256
    const float* __restrict__ b1,   // 256
    const float* __restrict__ bp,   // 256
    const float* __restrict__ W_arc,// 256
    const float* __restrict__ W_lab,// 256 x 45
    const float* __restrict__ b_lab,// 45
    const int* __restrict__ slens, const int* __restrict__ arcs,
    const int* __restrict__ labels,
    float* __restrict__ h, float* __restrict__ u, float* __restrict__ hv,
    float* __restrict__ vroot, float* __restrict__ accum,
    float* __restrict__ out)
{
    __shared__ __align__(16) char smem[SMEM_BYTES];
    cg::grid_group grid = cg::this_grid();
    int B = blockIdx.x;            // 0..255
    int tid = threadIdx.x;         // 0..511
    int sub = tid >> 8;            // 0..1 (phase A/B sub-block)
    int stid = tid & 255;

    if (B == 0 && tid == 0) accum[0] = 0.f;   // ws poisoned

    // ================= Phase A: hidden partials (k1) =================
    {
        // per-sub LDS: As[2][16][36] (1152 f) + Bs[2][16][68] (2176 f)
        float* As_ = (float*)smem + sub * 3328;
        float* Bs_ = As_ + 1152;
        int t = B * 2 + sub;                 // 0..511 k1 tiles
        int m0 = (t & 63) * 32;
        int n0 = ((t >> 6) & 3) * 64;
        int z  = t >> 8;
        int kbase = z * 256;

        int lm = stid >> 2, lk = (stid & 3) * 4;   // A-stage (stid<128)
        int bk = stid >> 4, bn = (stid & 15) * 4;  // B-stage
        int tm = stid >> 4, tn = stid & 15;        // compute 2x4
        float acc[2][4] = {{0.f}};
        float4 a_r, b_r;

        auto LOADK = [&](int c) {
            int k0 = kbase + c * 16;
            if (stid < 128)
                a_r = *(const float4*)&A[(size_t)(m0 + lm) * DIN + k0 + lk];
            b_r = *(const float4*)&W1[(size_t)(k0 + bk) * NH + n0 + bn];
        };
        auto WRITE = [&](int buf) {
            if (stid < 128) {
                As_[buf*576 + (lk+0)*36 + lm] = a_r.x;
                As_[buf*576 + (lk+1)*36 + lm] = a_r.y;
                As_[buf*576 + (lk+2)*36 + lm] = a_r.z;
                As_[buf*576 + (lk+3)*36 + lm] = a_r.w;
            }
            *(float4*)&Bs_[buf*1088 + bk*68 + bn] = b_r;
        };

        LOADK(0);
        WRITE(0);
        LOADK(1);
        __syncthreads();
        for (int c = 0; c < 16; ++c) {
            int buf = c & 1;
            #pragma unroll
            for (int kk = 0; kk < 16; kk++) {
                float2 a2 = *(const float2*)&As_[buf*576 + kk*36 + tm*2];
                float4 bv = *(const float4*)&Bs_[buf*1088 + kk*68 + tn*4];
                float ar[2] = {a2.x, a2.y};
                float br[4] = {bv.x, bv.y, bv.z, bv.w};
                #pragma unroll
                for (int r = 0; r < 2; r++)
                    #pragma unroll
                    for (int cc = 0; cc < 4; cc++)
                        acc[r][cc] = fmaf(ar[r], br[cc], acc[r][cc]);
            }
            if (c < 15) {
                WRITE(buf ^ 1);
                if (c < 14) LOADK(c + 2);
                __syncthreads();
            }
        }
        float* hz = h + (size_t)z * NM * NH;
        int col = n0 + tn * 4;
        #pragma unroll
        for (int r = 0; r < 2; r++) {
            int row = m0 + tm * 2 + r;
            *(float4*)&hz[(size_t)row * NH + col] =
                make_float4(acc[r][0], acc[r][1], acc[r][2], acc[r][3]);
        }

        // ---- vroot epilogue (tiles x==63,z==1); barriers UNCONDITIONAL ----
        bool q = ((t & 63) == 63) && (z == 1);
        float* part_ = (float*)(smem + 26624) + sub * 256;  // 4x64 per sub
        float p = 0.f;
        int vcol = n0 + (stid & 63);
        int kc = stid >> 6;
        if (q) {
            #pragma unroll 8
            for (int c = kc * 64; c < kc * 64 + 64; c++)
                p += root[c] * Wp[(size_t)(NH + c) * NH + vcol];
        }
        __syncthreads();
        if (q) part_[kc * 64 + (stid & 63)] = p;
        __syncthreads();
        if (q && stid < 64)
            vroot[n0 + stid] = part_[0*64+stid] + part_[1*64+stid]
                             + part_[2*64+stid] + part_[3*64+stid];
    }
    grid.sync();

    // ================= Phase B: u/hv (k2) =================
    {
        // per-sub LDS: As[2][16][68] (2176 f) + Bs[2][16][36] (1152 f)
        float* As_ = (float*)smem + sub * 3328;
        float* Bs_ = As_ + 2176;
        int t = B * 2 + sub;                 // 0..511 k2 tiles
        int m0 = (t & 31) * 64;
        int n0 = (t >> 5) * 32;
        bool isU = (n0 < NH);

        int arow = stid >> 2, akq = (stid & 3) * 4;  // A-stage: 64 x 16k
        int bk = stid >> 3, bn = (stid & 7) * 4;     // B-stage (stid<128)
        int tm = stid >> 3, tn = stid & 7;           // compute 2x4
        float acc[2][4] = {{0.f}};
        float4 ha_r, hb_r, bi_r, b_r;

        auto LOADK = [&](int c) {
            int k0 = c * 16;
            size_t base = (size_t)(m0 + arow) * NH + k0 + akq;
            ha_r = *(const float4*)&h[base];
            hb_r = *(const float4*)&h[base + (size_t)NM * NH];
            bi_r = *(const float4*)&b1[k0 + akq];
            if (stid < 128) {
                int ck = k0 + bk;
                if (isU) b_r = *(const float4*)&Wp[(size_t)ck * NH + n0 + bn];
                else     b_r = *(const float4*)&Wp[(size_t)(NH + ck) * NH + (n0 - NH) + bn];
            }
        };
        auto WRITE = [&](int buf) {
            As_[buf*1088 + (akq+0)*68 + arow] = fmaxf(ha_r.x + hb_r.x + bi_r.x, 0.f);
            As_[buf*1088 + (akq+1)*68 + arow] = fmaxf(ha_r.y + hb_r.y + bi_r.y, 0.f);
            As_[buf*1088 + (akq+2)*68 + arow] = fmaxf(ha_r.z + hb_r.z + bi_r.z, 0.f);
            As_[buf*1088 + (akq+3)*68 + arow] = fmaxf(ha_r.w + hb_r.w + bi_r.w, 0.f);
            if (stid < 128)
                *(float4*)&Bs_[buf*576 + bk*36 + bn] = b_r;
        };

        LOADK(0);
        WRITE(0);
        LOADK(1);
        __syncthreads();
        for (int c = 0; c < 16; ++c) {
            int buf = c & 1;
            #pragma unroll
            for (int kk = 0; kk < 16; kk++) {
                float2 a2 = *(const float2*)&As_[buf*1088 + kk*68 + tm*2];
                float4 bv = *(const float4*)&Bs_[buf*576 + kk*36 + tn*4];
                float ar[2] = {a2.x, a2.y};
                float br[4] = {bv.x, bv.y, bv.z, bv.w};
                #pragma unroll
                for (int r = 0; r < 2; r++)
                    #pragma unroll
                    for (int cc = 0; cc < 4; cc++)
                        acc[r][cc] = fmaf(ar[r], br[cc], acc[r][cc]);
            }
            if (c < 15) {
                WRITE(buf ^ 1);
                if (c < 14) LOADK(c + 2);
                __syncthreads();
            }
        }
        if (isU) {
            int col = n0 + tn * 4;
            float4 bb = *(const float4*)&bp[col];
            #pragma unroll
            for (int r = 0; r < 2; r++) {
                int row = m0 + tm * 2 + r;
                *(float4*)&u[(size_t)row * NH + col] = make_float4(
                    acc[r][0] + bb.x, acc[r][1] + bb.y,
                    acc[r][2] + bb.z, acc[r][3] + bb.w);
            }
        } else {
            int col = (n0 - NH) + tn * 4;
            #pragma unroll
            for (int r = 0; r < 2; r++) {
                int row = m0 + tm * 2 + r;
                *(float4*)&hv[(size_t)row * NH + col] = make_float4(
                    acc[r][0], acc[r][1], acc[r][2], acc[r][3]);
            }
        }
    }
    grid.sync();

    // ================= Phase C: scores + loss (k3, round-14) =================
    {
        float2* v2   = (float2*)smem;               // [kk2*130 + j] 133,120 B
        float2* u2   = (float2*)(smem + 133120);    // [r*128 + kk2]   8,192 B
        float2* wa2  = (float2*)(smem + 141312);    //                 1,024 B
        float2* sel2 = (float2*)(smem + 142336);    // [kk2*9 + w]     2,304 B
        float*  ce_s = (float*)(smem + 144640);
        int*    arc_s = (int*)(smem + 144672);
        int*    lab_s = arc_s + 8;

        int bb = B >> 4;
        int i0 = (B & 15) * 8;
        int w = tid >> 6;          // wave = local row (0..7)
        int lane = tid & 63;
        int slen = slens[bb];

        if (i0 < slen) {
            // ---- one-time staging: u rows, W_arc, arcs/labels ----
            {
                int r = tid >> 6, kq = (tid & 63) * 4;
                float4 a4 = *(const float4*)&u[(size_t)(bb * NL + i0 + r) * NH + kq];
                u2[r*128 + (kq >> 1) + 0] = make_float2(a4.x, a4.y);
                u2[r*128 + (kq >> 1) + 1] = make_float2(a4.z, a4.w);
            }
            if (tid < 128)
                wa2[tid] = *(const float2*)&W_arc[tid * 2];
            if (tid < 8) {
                int rg = bb * NL + i0 + tid;
                arc_s[tid] = arcs[rg];
                lab_s[tid] = labels[rg];
            }

            // ---- v stage: hv rows 0..127 -> cols 1..128; vroot -> col 0 ----
            {
                int jo  = lane >> 4;
                int kf0 = lane & 15;
                #pragma unroll
                for (int sj = 0; sj < 4; ++sj) {
                    int j = sj * 32 + w * 4 + jo;
                    const float* src = hv + (size_t)(bb * NL + j) * NH;
                    #pragma unroll
                    for (int sk = 0; sk < 4; ++sk) {
                        int kf = sk * 16 + kf0;
                        float4 t4 = *(const float4*)&src[kf * 4];
                        v2[(2*kf + 0)*130 + j + 1] = make_float2(t4.x, t4.y);
                        v2[(2*kf + 1)*130 + j + 1] = make_float2(t4.z, t4.w);
                    }
                }
                if (w == 0) {
                    float4 t4 = *(const float4*)&vroot[lane * 4];
                    v2[(2*lane + 0)*130 + 0] = make_float2(t4.x, t4.y);
                    v2[(2*lane + 1)*130 + 0] = make_float2(t4.z, t4.w);
                }
            }
            __syncthreads();

            float acc1 = 0.f, acc2 = 0.f, s128 = 0.f, lacc = 0.f;
            int a = arc_s[w];

            __builtin_amdgcn_s_setprio(1);
            #pragma unroll
            for (int c = 0; c < 4; ++c) {
                int k0 = c * 64;
                int kb = k0 >> 1;
                const float2* urow = u2 + w*128 + kb;
                const float2* warow = wa2 + kb;

                // arc scores: lane owns j=2*lane, 2*lane+1 (one b128/kk2)
                #pragma unroll 8
                for (int kk2 = 0; kk2 < 32; ++kk2) {
                    float2 u2v = urow[kk2];
                    float2 w2v = warow[kk2];
                    float4 q = *(const float4*)&v2[(kb + kk2)*130 + 2*lane];
                    acc1 += fmaxf(u2v.x + q.x, 0.f) * w2v.x
                          + fmaxf(u2v.y + q.y, 0.f) * w2v.y;
                    acc2 += fmaxf(u2v.x + q.z, 0.f) * w2v.x
                          + fmaxf(u2v.y + q.w, 0.f) * w2v.y;
                }
                // j=128 partial + sel staging (lanes 0..31 own kk2=lane)
                if (lane < 32) {
                    float2 u2v = urow[lane];
                    float2 w2v = warow[lane];
                    float2 vv = v2[(kb + lane)*130 + 128];
                    s128 += fmaxf(u2v.x + vv.x, 0.f) * w2v.x
                          + fmaxf(u2v.y + vv.y, 0.f) * w2v.y;
                    float2 vs = v2[(kb + lane)*130 + a];
                    sel2[lane*9 + w] = make_float2(fmaxf(u2v.x + vs.x, 0.f),
                                                   fmaxf(u2v.y + vs.y, 0.f));
                }
                // label logit partials: lane = tag, W_lab direct (L1)
                if (lane < NTAGS) {
                    #pragma unroll 8
                    for (int kk2 = 0; kk2 < 32; ++kk2) {
                        float2 s2 = sel2[kk2*9 + w];
                        float w0 = W_lab[(size_t)(k0 + 2*kk2) * NTAGS + lane];
                        float w1 = W_lab[(size_t)(k0 + 2*kk2 + 1) * NTAGS + lane];
                        lacc = fmaf(s2.x, w0, fmaf(s2.y, w1, lacc));
                    }
                }
            }
            __builtin_amdgcn_s_setprio(0);

            // ---- arc softmax CE ----
            float s128t = s128;
            #pragma unroll
            for (int off = 32; off > 0; off >>= 1)
                s128t += __shfl_xor(s128t, off);
            float m = fmaxf(acc1, acc2);
            #pragma unroll
            for (int off = 32; off > 0; off >>= 1)
                m = fmaxf(m, __shfl_xor(m, off));
            m = fmaxf(m, s128t);
            float e = expf(acc1 - m) + expf(acc2 - m);
            #pragma unroll
            for (int off = 32; off > 0; off >>= 1)
                e += __shfl_xor(e, off);
            e += expf(s128t - m);
            float cand = (a & 1) ? acc2 : acc1;
            float s_a = __shfl(cand, (a >> 1) & 63, 64);
            if (a == 128) s_a = s128t;
            float arc_ce = (m + logf(e)) - s_a;

            // ---- label softmax CE ----
            float logit = (lane < NTAGS) ? (lacc + b_lab[lane]) : -INFINITY;
            float m2 = logit;
            #pragma unroll
            for (int off = 32; off > 0; off >>= 1)
                m2 = fmaxf(m2, __shfl_xor(m2, off));
            float e2 = (lane < NTAGS) ? expf(logit - m2) : 0.f;
            #pragma unroll
            for (int off = 32; off > 0; off >>= 1)
                e2 += __shfl_xor(e2, off);
            float l_t = __shfl(logit, lab_s[w], 64);
            float lab_ce = (m2 + logf(e2)) - l_t;

            float tot = ((i0 + w) < slen) ? (arc_ce + lab_ce) : 0.f;
            if (lane == 0) ce_s[w] = tot;
            __syncthreads();
            if (tid == 0)
                atomicAdd(accum, ce_s[0] + ce_s[1] + ce_s[2] + ce_s[3]
                               + ce_s[4] + ce_s[5] + ce_s[6] + ce_s[7]);
        }
    }
    grid.sync();

    // ================= finalize =================
    if (B == 0 && tid == 0) {
        int d = 0;
        #pragma unroll
        for (int q = 0; q < NB; ++q) d += slens[q];
        float s = atomicAdd(accum, 0.f);   // device-scope read
        out[0] = 0.5f * s / fmaxf((float)d, 1.f);
    }
}

extern "C" void kernel_launch(void* const* d_in, const int* in_sizes, int n_in,
                              void* d_out, int out_size, void* d_ws, size_t ws_size,
                              hipStream_t stream) {
    (void)in_sizes; (void)n_in; (void)out_size; (void)ws_size;
    const float* ctx   = (const float*)d_in[0];
    const int*   slens = (const int*)  d_in[1];
    const int*   arcs  = (const int*)  d_in[2];
    const int*   labs  = (const int*)  d_in[3];
    const float* W1    = (const float*)d_in[4];
    const float* b1    = (const float*)d_in[5];
    const float* root  = (const float*)d_in[6];
    const float* Wp    = (const float*)d_in[7];
    const float* bp    = (const float*)d_in[8];
    const float* W_arc = (const float*)d_in[9];
    // d_in[10] = b_arc: constant shift, cancels in arc log-softmax CE
    const float* W_lab = (const float*)d_in[11];
    const float* b_lab = (const float*)d_in[12];
    float* out = (float*)d_out;

    float* ws    = (float*)d_ws;
    float* h     = ws + H_OFF;
    float* u     = ws + U_OFF;
    float* hv    = ws + HV_OFF;
    float* vroot = ws + VROOT_OFF;
    float* accum = ws + ACC_OFF;

    void* args[] = {
        (void*)&ctx, (void*)&W1, (void*)&Wp, (void*)&root,
        (void*)&b1, (void*)&bp, (void*)&W_arc, (void*)&W_lab, (void*)&b_lab,
        (void*)&slens, (void*)&arcs, (void*)&labs,
        (void*)&h, (void*)&u, (void*)&hv, (void*)&vroot, (void*)&accum,
        (void*)&out
    };
    hipLaunchCooperativeKernel((const void*)fused_kernel, dim3(256), dim3(512),
                               args, 0, stream);
}

// Round 18
// 127.380 us; speedup vs baseline: 1.7459x; 1.7459x over previous
//
#include <hip/hip_runtime.h>
#include <math.h>

// Problem constants
#define NB 16
#define NL 128
#define DIN 512
#define NH 256
#define NTAGS 45
#define NM (NB*NL)          // 2048 rows
#define NJ (NL+1)           // 129 arc columns

// ws layout (floats)
#define H_OFF     0                        // 2 slabs of NM*NH (k1 K-split partials)
#define U_OFF     (2*NM*NH)                // 1 slab  (u = hidden@Wa + bp)
#define HV_OFF    (3*NM*NH)                // 1 slab  (hv = hidden@Wb)
#define VROOT_OFF (4*NM*NH)                // NH
#define ACC_OFF   (VROOT_OFF + NH)         // [0]=loss sum, [1]=done counter (int)

// ---------------------------------------------------------------------------
// Kernel 1 (round-8 measured-good): hidden partials, K-split x2.
// 64x64 tile, 4x4/thread, BK=16, reg-staged dbuf pipeline (1 barrier/chunk).
// grid (32,4,2) = 256 blocks = 1/CU. 4x4 acc: 16 FMA per 2 LDS-b128 reads
// (vs 2x4's 8 FMA / 3 reads — round-9's re-tiling suspected hidden regression).
// bias+relu deferred to K2. Blocks (x==31, z==1) append the vroot epilogue.
// Block (0,0,0) zeroes the loss accumulator + done counter (ws poisoned).
// ---------------------------------------------------------------------------
__global__ __launch_bounds__(256) void gemm_hidden(
    const float* __restrict__ A,    // 2048 x 512
    const float* __restrict__ W,    // 512 x 256
    const float* __restrict__ Wp,   // 512 x 256 (for vroot epilogue)
    const float* __restrict__ root, // 256
    float* __restrict__ h,          // 2 x 2048 x 256 partials
    float* __restrict__ vroot,      // 256
    float* __restrict__ accum)
{
    __shared__ float As[2][16][68];   // [buf][k][m]
    __shared__ float Bs[2][16][68];   // [buf][k][n]
    __shared__ float part[4][64];     // vroot epilogue scratch
    int m0 = blockIdx.x * 64;
    int n0 = blockIdx.y * 64;
    int kbase = blockIdx.z * 256;
    int tid = threadIdx.x;
    if (blockIdx.x == 0 && blockIdx.y == 0 && blockIdx.z == 0 && tid == 0) {
        accum[0] = 0.f;
        ((int*)accum)[1] = 0;
    }
    int arow = tid >> 2, akq = (tid & 3) * 4;   // A-stage: 64 rows x 16 k
    int bk = tid >> 4, bn = (tid & 15) * 4;     // B-stage: 16 k x 64 n
    int tm = tid >> 4, tn = tid & 15;           // compute: 4 rows x 4 cols
    float acc[4][4] = {{0.f}};
    float4 a_r, b_r;

    auto LOADK = [&](int c) {
        int k0 = kbase + c * 16;
        a_r = *(const float4*)&A[(size_t)(m0 + arow) * DIN + k0 + akq];
        b_r = *(const float4*)&W[(size_t)(k0 + bk) * NH + n0 + bn];
    };
    auto WRITE = [&](int buf) {
        As[buf][akq + 0][arow] = a_r.x; As[buf][akq + 1][arow] = a_r.y;
        As[buf][akq + 2][arow] = a_r.z; As[buf][akq + 3][arow] = a_r.w;
        *(float4*)&Bs[buf][bk][bn] = b_r;
    };

    LOADK(0);
    WRITE(0);
    LOADK(1);
    __syncthreads();
    for (int c = 0; c < 16; ++c) {
        int buf = c & 1;
        #pragma unroll
        for (int kk = 0; kk < 16; kk++) {
            float4 av = *(const float4*)&As[buf][kk][tm * 4];
            float4 bv = *(const float4*)&Bs[buf][kk][tn * 4];
            float ar[4] = {av.x, av.y, av.z, av.w};
            float br[4] = {bv.x, bv.y, bv.z, bv.w};
            #pragma unroll
            for (int r = 0; r < 4; r++)
                #pragma unroll
                for (int cc = 0; cc < 4; cc++)
                    acc[r][cc] = fmaf(ar[r], br[cc], acc[r][cc]);
        }
        if (c < 15) {
            WRITE(buf ^ 1);          // stage chunk c+1 (loads issued iter c-1)
            if (c < 14) LOADK(c + 2);
            __syncthreads();
        }
    }
    float* hz = h + (size_t)blockIdx.z * NM * NH;
    int col = n0 + tn * 4;
    #pragma unroll
    for (int r = 0; r < 4; r++) {
        int row = m0 + tm * 4 + r;
        *(float4*)&hz[(size_t)row * NH + col] =
            make_float4(acc[r][0], acc[r][1], acc[r][2], acc[r][3]);
    }

    // ---- vroot epilogue on 4 blocks (x==31, z==1): cols n0..n0+63 ----
    if (blockIdx.x == 31 && blockIdx.z == 1) {
        __syncthreads();
        int vcol = n0 + (tid & 63);
        int kc = tid >> 6;
        float p = 0.f;
        #pragma unroll 8
        for (int c = kc * 64; c < kc * 64 + 64; c++)
            p += root[c] * Wp[(size_t)(NH + c) * NH + vcol];
        part[kc][tid & 63] = p;
        __syncthreads();
        if (tid < 64)
            vroot[n0 + tid] = part[0][tid] + part[1][tid]
                            + part[2][tid] + part[3][tid];
    }
}

// ---------------------------------------------------------------------------
// Kernel 2 (round-8 measured-good): u = hidden@Wa + bp ; hv = hidden@Wb
// hidden reconstructed on the fly: relu(h0 + h1 + b1) during A-stage.
// Full K=256 (single u/hv slabs; bp folded). 64x64 tile, 4x4/thread, BK=16,
// reg-staged dbuf pipeline. grid (32,8) = 256 blocks = 1/CU (no stragglers).
// ---------------------------------------------------------------------------
__global__ __launch_bounds__(256) void gemm_uv(
    const float* __restrict__ h,      // 2 x 2048 x 256 partials
    const float* __restrict__ b1,     // 256 (hidden bias)
    const float* __restrict__ Wp,     // 512 x 256
    const float* __restrict__ bp,     // 256 (pair bias)
    float* __restrict__ u,            // 2048 x 256
    float* __restrict__ hv)           // 2048 x 256
{
    __shared__ float As[2][16][68];
    __shared__ float Bs[2][16][68];
    int n0 = blockIdx.y * 64;
    int tid = threadIdx.x;
    int m0 = blockIdx.x * 64;
    bool isU = (n0 < NH);
    int arow = tid >> 2, akq = (tid & 3) * 4;
    int bk = tid >> 4, bn = (tid & 15) * 4;
    int tm = tid >> 4, tn = tid & 15;
    float acc[4][4] = {{0.f}};
    float4 ha_r, hb_r, bi_r, b_r;

    auto LOADK = [&](int c) {
        int k0 = c * 16;
        size_t base = (size_t)(m0 + arow) * NH + k0 + akq;
        ha_r = *(const float4*)&h[base];
        hb_r = *(const float4*)&h[base + (size_t)NM * NH];
        bi_r = *(const float4*)&b1[k0 + akq];
        int ck = k0 + bk;
        if (isU) b_r = *(const float4*)&Wp[(size_t)ck * NH + n0 + bn];
        else     b_r = *(const float4*)&Wp[(size_t)(NH + ck) * NH + (n0 - NH) + bn];
    };
    auto WRITE = [&](int buf) {
        As[buf][akq + 0][arow] = fmaxf(ha_r.x + hb_r.x + bi_r.x, 0.f);
        As[buf][akq + 1][arow] = fmaxf(ha_r.y + hb_r.y + bi_r.y, 0.f);
        As[buf][akq + 2][arow] = fmaxf(ha_r.z + hb_r.z + bi_r.z, 0.f);
        As[buf][akq + 3][arow] = fmaxf(ha_r.w + hb_r.w + bi_r.w, 0.f);
        *(float4*)&Bs[buf][bk][bn] = b_r;
    };

    LOADK(0);
    WRITE(0);
    LOADK(1);
    __syncthreads();
    for (int c = 0; c < 16; ++c) {
        int buf = c & 1;
        #pragma unroll
        for (int kk = 0; kk < 16; kk++) {
            float4 av = *(const float4*)&As[buf][kk][tm * 4];
            float4 bv = *(const float4*)&Bs[buf][kk][tn * 4];
            float ar[4] = {av.x, av.y, av.z, av.w};
            float br[4] = {bv.x, bv.y, bv.z, bv.w};
            #pragma unroll
            for (int r = 0; r < 4; r++)
                #pragma unroll
                for (int cc = 0; cc < 4; cc++)
                    acc[r][cc] = fmaf(ar[r], br[cc], acc[r][cc]);
        }
        if (c < 15) {
            WRITE(buf ^ 1);
            if (c < 14) LOADK(c + 2);
            __syncthreads();
        }
    }
    if (isU) {
        int col = n0 + tn * 4;
        float4 bb = *(const float4*)&bp[col];
        #pragma unroll
        for (int r = 0; r < 4; r++) {
            int row = m0 + tm * 4 + r;
            *(float4*)&u[(size_t)row * NH + col] = make_float4(
                acc[r][0] + bb.x, acc[r][1] + bb.y,
                acc[r][2] + bb.z, acc[r][3] + bb.w);
        }
    } else {
        int col = (n0 - NH) + tn * 4;
        #pragma unroll
        for (int r = 0; r < 4; r++) {
            int row = m0 + tm * 4 + r;
            *(float4*)&hv[(size_t)row * NH + col] = make_float4(
                acc[r][0], acc[r][1], acc[r][2], acc[r][3]);
        }
    }
}

// ---------------------------------------------------------------------------
// Kernel 3 (round-14 proven best): fused scores+loss+finalize.
// 8 rows/block (512 thr, wave = row), grid (NB,16) = 256 blocks = 1/CU.
// Full v-tile staged once (133 KB LDS, [kk2][j] float2, rows padded to 130
// = 16B-aligned). Lane owns j = 2*lane, 2*lane+1 -> one aligned ds_read_b128
// per kk2 (conflict-free). u/wa/sel via LDS broadcasts, unroll 8 (readlane/
// full-unroll variants spilled, excluded). One atomicAdd per block;
// done-counter finalize.
// ---------------------------------------------------------------------------
#define NBLK (NB*16)   // 256

__global__ __launch_bounds__(512) void score_loss_kernel(
    const float* __restrict__ u, const float* __restrict__ hv,
    const float* __restrict__ vroot, const float* __restrict__ W_arc,
    const float* __restrict__ W_lab, const float* __restrict__ b_lab,
    const int* __restrict__ slens, const int* __restrict__ arcs,
    const int* __restrict__ labels,
    float* __restrict__ accum, float* __restrict__ out)
{
    __shared__ float2 v2_s[128][130];  // [kk2][j], row 1040 B  133,120 B
    __shared__ float2 u2_s[8][128];    // [row][kk2]              8,192 B
    __shared__ float2 wa2_s[128];      //                         1,024 B
    __shared__ float2 sel2_s[32][9];   // [kk2][row]              2,304 B
    __shared__ float  ce_s[8];
    __shared__ int    arc_s[8], lab_s[8];

    int bb = blockIdx.x;
    int i0 = blockIdx.y * 8;
    int tid = threadIdx.x;
    int w = tid >> 6;          // wave index = local row (0..7)
    int lane = tid & 63;
    int slen = slens[bb];

    if (i0 < slen) {
        // ---- one-time staging: u rows, W_arc, arcs/labels ----
        {
            int r = tid >> 6, kq = (tid & 63) * 4;   // 8 rows x 64 float4
            float4 a4 = *(const float4*)&u[(size_t)(bb * NL + i0 + r) * NH + kq];
            u2_s[r][(kq >> 1) + 0] = make_float2(a4.x, a4.y);
            u2_s[r][(kq >> 1) + 1] = make_float2(a4.z, a4.w);
        }
        if (tid < 128)
            wa2_s[tid] = *(const float2*)&W_arc[tid * 2];
        if (tid < 8) {
            int rg = bb * NL + i0 + tid;
            arc_s[tid] = arcs[rg];
            lab_s[tid] = labels[rg];
        }

        // ---- v stage (once): hv rows 0..127 -> v cols 1..128; vroot -> col 0.
        {
            int jo  = lane >> 4;         // 0..3
            int kf0 = lane & 15;         // 0..15
            #pragma unroll
            for (int sj = 0; sj < 4; ++sj) {
                int j = sj * 32 + w * 4 + jo;        // hv row 0..127
                const float* src = hv + (size_t)(bb * NL + j) * NH;
                #pragma unroll
                for (int sk = 0; sk < 4; ++sk) {
                    int kf = sk * 16 + kf0;          // float4 col 0..63
                    float4 t4 = *(const float4*)&src[kf * 4];
                    v2_s[2 * kf + 0][j + 1] = make_float2(t4.x, t4.y);
                    v2_s[2 * kf + 1][j + 1] = make_float2(t4.z, t4.w);
                }
            }
            if (w == 0) {                            // vroot -> col 0
                float4 t4 = *(const float4*)&vroot[lane * 4];
                v2_s[2 * lane + 0][0] = make_float2(t4.x, t4.y);
                v2_s[2 * lane + 1][0] = make_float2(t4.z, t4.w);
            }
        }
        __syncthreads();

        float acc1 = 0.f, acc2 = 0.f, s128 = 0.f, lacc = 0.f;
        int a = arc_s[w];

        __builtin_amdgcn_s_setprio(1);
        #pragma unroll
        for (int c = 0; c < 4; ++c) {
            int k0 = c * 64;
            int kb = k0 >> 1;            // base kk2 row in v2_s
            const float2* urow = u2_s[w] + kb;
            const float2* warow = wa2_s + kb;

            // ---- arc scores: lane owns j=2*lane, 2*lane+1 (one b128/kk2) ----
            #pragma unroll 8
            for (int kk2 = 0; kk2 < 32; ++kk2) {
                float2 u2 = urow[kk2];
                float2 w2 = warow[kk2];
                float4 q = *(const float4*)&v2_s[kb + kk2][2 * lane];
                acc1 += fmaxf(u2.x + q.x, 0.f) * w2.x
                      + fmaxf(u2.y + q.y, 0.f) * w2.y;
                acc2 += fmaxf(u2.x + q.z, 0.f) * w2.x
                      + fmaxf(u2.y + q.w, 0.f) * w2.y;
            }
            // ---- j=128 partial + sel staging (lanes 0..31 own kk2=lane) ----
            if (lane < 32) {
                float2 u2 = urow[lane];
                float2 w2 = warow[lane];
                float2 vv = v2_s[kb + lane][128];
                s128 += fmaxf(u2.x + vv.x, 0.f) * w2.x
                      + fmaxf(u2.y + vv.y, 0.f) * w2.y;
                float2 vs = v2_s[kb + lane][a];
                sel2_s[lane][w] = make_float2(fmaxf(u2.x + vs.x, 0.f),
                                              fmaxf(u2.y + vs.y, 0.f));
            }
            // ---- label logit partials: lane = tag, W_lab direct (L1) ----
            if (lane < NTAGS) {
                #pragma unroll 8
                for (int kk2 = 0; kk2 < 32; ++kk2) {
                    float2 s2 = sel2_s[kk2][w];
                    float w0 = W_lab[(size_t)(k0 + 2 * kk2) * NTAGS + lane];
                    float w1 = W_lab[(size_t)(k0 + 2 * kk2 + 1) * NTAGS + lane];
                    lacc = fmaf(s2.x, w0, fmaf(s2.y, w1, lacc));
                }
            }
        }
        __builtin_amdgcn_s_setprio(0);

        // ---- arc softmax CE (full-wave shuffles) ----
        float s128t = s128;
        #pragma unroll
        for (int off = 32; off > 0; off >>= 1)
            s128t += __shfl_xor(s128t, off);
        float m = fmaxf(acc1, acc2);
        #pragma unroll
        for (int off = 32; off > 0; off >>= 1)
            m = fmaxf(m, __shfl_xor(m, off));
        m = fmaxf(m, s128t);
        float e = expf(acc1 - m) + expf(acc2 - m);
        #pragma unroll
        for (int off = 32; off > 0; off >>= 1)
            e += __shfl_xor(e, off);
        e += expf(s128t - m);
        // lane a>>1 holds score j=a: acc1 if a even, acc2 if a odd
        float cand = (a & 1) ? acc2 : acc1;
        float s_a = __shfl(cand, (a >> 1) & 63, 64);
        if (a == 128) s_a = s128t;
        float arc_ce = (m + logf(e)) - s_a;

        // ---- label softmax CE ----
        float logit = (lane < NTAGS) ? (lacc + b_lab[lane]) : -INFINITY;
        float m2 = logit;
        #pragma unroll
        for (int off = 32; off > 0; off >>= 1)
            m2 = fmaxf(m2, __shfl_xor(m2, off));
        float e2 = (lane < NTAGS) ? expf(logit - m2) : 0.f;
        #pragma unroll
        for (int off = 32; off > 0; off >>= 1)
            e2 += __shfl_xor(e2, off);
        float l_t = __shfl(logit, lab_s[w], 64);
        float lab_ce = (m2 + logf(e2)) - l_t;

        float tot = ((i0 + w) < slen) ? (arc_ce + lab_ce) : 0.f;
        if (lane == 0) ce_s[w] = tot;
        __syncthreads();
        if (tid == 0)
            atomicAdd(accum, ce_s[0] + ce_s[1] + ce_s[2] + ce_s[3]
                           + ce_s[4] + ce_s[5] + ce_s[6] + ce_s[7]);
    }

    // ---- done counter; last block finalizes ----
    if (tid == 0) {
        __threadfence();
        int prev = atomicAdd((int*)accum + 1, 1);
        if (prev == NBLK - 1) {
            int d = 0;
            #pragma unroll
            for (int q = 0; q < NB; ++q) d += slens[q];
            float s = atomicAdd(accum, 0.f);   // coherent read
            out[0] = 0.5f * s / fmaxf((float)d, 1.f);
        }
    }
}

extern "C" void kernel_launch(void* const* d_in, const int* in_sizes, int n_in,
                              void* d_out, int out_size, void* d_ws, size_t ws_size,
                              hipStream_t stream) {
    (void)in_sizes; (void)n_in; (void)out_size; (void)ws_size;
    const float* ctx   = (const float*)d_in[0];
    const int*   slens = (const int*)  d_in[1];
    const int*   arcs  = (const int*)  d_in[2];
    const int*   labs  = (const int*)  d_in[3];
    const float* W1    = (const float*)d_in[4];
    const float* b1    = (const float*)d_in[5];
    const float* root  = (const float*)d_in[6];
    const float* Wp    = (const float*)d_in[7];
    const float* bp    = (const float*)d_in[8];
    const float* W_arc = (const float*)d_in[9];
    // d_in[10] = b_arc: constant shift, cancels in arc log-softmax CE
    const float* W_lab = (const float*)d_in[11];
    const float* b_lab = (const float*)d_in[12];
    float* out = (float*)d_out;

    float* ws    = (float*)d_ws;
    float* h     = ws + H_OFF;
    float* u     = ws + U_OFF;
    float* hv    = ws + HV_OFF;
    float* vroot = ws + VROOT_OFF;
    float* accum = ws + ACC_OFF;

    gemm_hidden<<<dim3(32, 4, 2), 256, 0, stream>>>(ctx, W1, Wp, root, h, vroot, accum);
    gemm_uv<<<dim3(32, 8), 256, 0, stream>>>(h, b1, Wp, bp, u, hv);
    score_loss_kernel<<<dim3(NB, 16), 512, 0, stream>>>(
        u, hv, vroot, W_arc, W_lab, b_lab, slens, arcs, labs, accum, out);
}